// Round 5
// baseline (1217.106 us; speedup 1.0000x reference)
//
#include <hip/hip_runtime.h>
#include <math.h>

// PatchTST-style fused forward, f32 in/out, bf16 MFMA compute.
// Round-5: occupancy attack. LDS 60.9KB -> 50.7KB (drop bufC via deferred-v
// attention; pred_s shrunk to 30 rows) => 3 blocks/CU (24 waves) instead of 2.
// Attention split: [q,k gemm] [score update + rowmax] [v gemm over q's buffer]
// [softmax+PV fused (ssum computed here)] -> o over k's buffer.
// __launch_bounds__(512,6): 6 waves/SIMD min => VGPR cap 85 (we use ~70).

typedef unsigned short u16;
typedef __attribute__((ext_vector_type(8))) short short8;
typedef __attribute__((ext_vector_type(4))) float floatx4;

#define ATTN_SCALE 0.35355339059327373f  // 8^-0.5
#define SB 136   // bf16 LDS row stride: 272B = 68 dwords, 68%32=4 -> bank rotation
#define SF 132   // f32  LDS row stride: 132 dwords, 132%32=4

#define MFMA_BF16 __builtin_amdgcn_mfma_f32_16x16x32_bf16

__device__ __forceinline__ u16 f2bf(float f){
  union{float f; unsigned u;} v; v.f=f;
  unsigned r = v.u + 0x7FFFu + ((v.u>>16)&1u);   // RNE
  return (u16)(r>>16);
}
__device__ __forceinline__ float bf2f(u16 h){
  union{unsigned u; float f;} v; v.u = ((unsigned)h)<<16;
  return v.f;
}
__device__ __forceinline__ float gelu_f(float x){   // tanh-form gelu (sigmoid identity)
  float u = x*(1.f + 0.044715f*x*x);
  float e = __expf(-1.5957691216057308f*u);
  return x/(1.f+e);
}

// 8 f32 -> bf16 fragment (16B-aligned source)
__device__ __forceinline__ short8 cvt8(const float* ap){
  floatx4 f0 = *(const floatx4*)ap;
  floatx4 f1 = *(const floatx4*)(ap+4);
  short8 a;
  a[0]=(short)f2bf(f0[0]); a[1]=(short)f2bf(f0[1]);
  a[2]=(short)f2bf(f0[2]); a[3]=(short)f2bf(f0[3]);
  a[4]=(short)f2bf(f1[0]); a[5]=(short)f2bf(f1[1]);
  a[6]=(short)f2bf(f1[2]); a[7]=(short)f2bf(f1[3]);
  return a;
}
__device__ __forceinline__ short8 loadB(const u16* p){ return *(const short8*)p; }
__device__ __forceinline__ short8 loadB(const float* p){ return cvt8(p); }

// epilogue: store 4 acc rows (+bias) as bf16, zero rows >=30
__device__ __forceinline__ void epi(u16* out, floatx4 acc, float bv, int rt, int qd, int col){
  #pragma unroll
  for (int r=0;r<4;++r){
    const int row = rt*16+qd*4+r;
    out[row*SB+col] = (row<30) ? f2bf(acc[r]+bv) : (u16)0;
  }
}

// out(30x128) = A(32x128 LDS bf16) @ W^T + bias. Both row-tiles share B (ct=wave).
template<typename WT>
__device__ __forceinline__ void gemm2(const u16* A, const WT* __restrict__ W,
                                      const float* __restrict__ bias, u16* out,
                                      int wave, int lane){
  const int m=lane&15, qd=lane>>4, col=wave*16+m;
  short8 b4[4];
  #pragma unroll
  for (int kt=0;kt<4;++kt) b4[kt] = loadB(W + col*128 + kt*32 + qd*8);
  const float bv = bias[col];
  #pragma unroll
  for (int rt=0;rt<2;++rt){
    short8 a4[4];
    #pragma unroll
    for (int kt=0;kt<4;++kt) a4[kt] = *(const short8*)(A + (rt*16+m)*SB + kt*32 + qd*8);
    floatx4 acc = {0.f,0.f,0.f,0.f};
    #pragma unroll
    for (int kt=0;kt<4;++kt) acc = MFMA_BF16(a4[kt], b4[kt], acc, 0,0,0);
    epi(out, acc, bv, rt, qd, col);
  }
}

// q and k gemms (different A): B-loads for both batched up front.
template<typename WT>
__device__ __forceinline__ void gemm_qk(const u16* Aq, const u16* Ak,
                                        const WT* __restrict__ Wq, const float* __restrict__ bq,
                                        const WT* __restrict__ Wk, const float* __restrict__ bk,
                                        u16* outq, u16* outk, int wave, int lane){
  const int m=lane&15, qd=lane>>4, col=wave*16+m;
  short8 bqf[4], bkf[4];
  #pragma unroll
  for (int kt=0;kt<4;++kt) bqf[kt] = loadB(Wq + col*128 + kt*32 + qd*8);
  #pragma unroll
  for (int kt=0;kt<4;++kt) bkf[kt] = loadB(Wk + col*128 + kt*32 + qd*8);
  const float bqb = bq[col], bkb = bk[col];
  #pragma unroll
  for (int rt=0;rt<2;++rt){
    short8 aq4[4], ak4[4];
    #pragma unroll
    for (int kt=0;kt<4;++kt){
      aq4[kt] = *(const short8*)(Aq + (rt*16+m)*SB + kt*32 + qd*8);
      ak4[kt] = *(const short8*)(Ak + (rt*16+m)*SB + kt*32 + qd*8);
    }
    floatx4 accq = {0.f,0.f,0.f,0.f}, acck = {0.f,0.f,0.f,0.f};
    #pragma unroll
    for (int kt=0;kt<4;++kt){
      accq = MFMA_BF16(aq4[kt], bqf[kt], accq, 0,0,0);
      acck = MFMA_BF16(ak4[kt], bkf[kt], acck, 0,0,0);
    }
    epi(outq, accq, bqb, rt, qd, col);
    epi(outk, acck, bkb, rt, qd, col);
  }
}

// FF up: h = pred@W1^T (256 cols); writes ag = a * gelu(gate) directly.
template<typename WT>
__device__ __forceinline__ void gemm_h(const u16* A, const WT* __restrict__ W1,
                                       const float* __restrict__ b1, u16* out,
                                       int wave, int lane){
  const int m=lane&15, qd=lane>>4, col=wave*16+m;
  short8 ba4[4], bg4[4];
  #pragma unroll
  for (int kt=0;kt<4;++kt) ba4[kt] = loadB(W1 + col*128 + kt*32 + qd*8);
  #pragma unroll
  for (int kt=0;kt<4;++kt) bg4[kt] = loadB(W1 + (128+col)*128 + kt*32 + qd*8);
  const float bab = b1[col], bgb = b1[128+col];
  #pragma unroll
  for (int rt=0;rt<2;++rt){
    short8 a4[4];
    #pragma unroll
    for (int kt=0;kt<4;++kt) a4[kt] = *(const short8*)(A + (rt*16+m)*SB + kt*32 + qd*8);
    floatx4 acca = {0.f,0.f,0.f,0.f}, accg = {0.f,0.f,0.f,0.f};
    #pragma unroll
    for (int kt=0;kt<4;++kt){
      acca = MFMA_BF16(a4[kt], ba4[kt], acca, 0,0,0);
      accg = MFMA_BF16(a4[kt], bg4[kt], accg, 0,0,0);
    }
    #pragma unroll
    for (int r=0;r<4;++r){
      const int row = rt*16+qd*4+r;
      u16 res = 0;
      if (row<30){
        float a = acca[r]+bab;
        float g = accg[r]+bgb;
        res = f2bf(a * gelu_f(g));
      }
      out[row*SB+col] = res;
    }
  }
}

// pred = LN(pred + bf16(add)) * g + be, rows 0..29; maintains bf16 mirror predb
__device__ __forceinline__ void ln_res(float* pred, u16* predb, const u16* add,
                                       const float* __restrict__ g, const float* __restrict__ be,
                                       int wave, int lane){
  for (int rr=wave; rr<30; rr+=8){
    float* pr = pred + rr*SF;
    u16*  pbr = predb + rr*SB;
    const u16* ar = add + rr*SB;
    float v0 = pr[lane]    + bf2f(ar[lane]);
    float v1 = pr[lane+64] + bf2f(ar[lane+64]);
    float s = v0+v1, s2 = v0*v0+v1*v1;
    #pragma unroll
    for (int off=32; off>0; off>>=1){ s += __shfl_xor(s,off,64); s2 += __shfl_xor(s2,off,64); }
    float m = s*(1.f/128.f);
    float var = s2*(1.f/128.f) - m*m;
    float rstd = rsqrtf(var + 1e-5f);
    float o0 = (v0-m)*rstd*g[lane]    + be[lane];
    float o1 = (v1-m)*rstd*g[lane+64] + be[lane+64];
    pr[lane] = o0; pr[lane+64] = o1;
    pbr[lane] = f2bf(o0); pbr[lane+64] = f2bf(o1);
  }
}

// f32 -> bf16 weight staging
__global__ void cvtw(const float* __restrict__ Wq, const float* __restrict__ Wk,
                     const float* __restrict__ Wv, const float* __restrict__ Wo,
                     const float* __restrict__ W1, const float* __restrict__ W2,
                     u16* __restrict__ ws){
  const int i = blockIdx.x*256 + threadIdx.x;   // grid covers exactly 344064
  float v;
  if      (i < 49152)  v = Wq[i];
  else if (i < 98304)  v = Wk[i-49152];
  else if (i < 147456) v = Wv[i-98304];
  else if (i < 196608) v = Wo[i-147456];
  else if (i < 294912) v = W1[i-196608];
  else                 v = W2[i-294912];
  ws[i] = f2bf(v);
}

template<typename WT>
__global__ __launch_bounds__(512, 6) void ts_fused(
  const float* __restrict__ z,    const float* __restrict__ WPw, const float* __restrict__ WPb,
  const float* __restrict__ PE,   const float* __restrict__ dums,
  const WT*    __restrict__ Wq_a, const float* __restrict__ bq_a,
  const WT*    __restrict__ Wk_a, const float* __restrict__ bk_a,
  const WT*    __restrict__ Wv_a, const float* __restrict__ bv_a,
  const WT*    __restrict__ Wo_a, const float* __restrict__ bo_a,
  const float* __restrict__ g1_a, const float* __restrict__ be1_a,
  const WT*    __restrict__ W1_a, const float* __restrict__ b1_a,
  const WT*    __restrict__ W2_a, const float* __restrict__ b2_a,
  const float* __restrict__ g2_a, const float* __restrict__ be2_a,
  const float* __restrict__ PJw,  const float* __restrict__ PJb,
  float* __restrict__ dout)
{
  __shared__ __align__(16) u16   x_s[32*SB];      // encoder tokens (rows 30,31 = 0)
  __shared__ __align__(16) u16   predb[32*SB];    // bf16 mirror of pred
  __shared__ __align__(16) float pred_s[30*SF];   // decoder state, f32 (30 rows)
  __shared__ __align__(16) u16   bufA[32*SB];     // zn / q -> v -> wo / ag
  __shared__ __align__(16) u16   bufB[32*SB];     // k -> o / h
  __shared__ float redA[8], redB[8], stats[2];

  const int tid  = threadIdx.x;
  const int wave = tid >> 6;
  const int lane = tid & 63;
  const int bi   = blockIdx.x;          // 0..5135 = b*321+c
  const int c    = bi % 321;
  const float* zr = z + bi*720;

  // ---- per-series mean/std over 720 samples ----
  float s=0.f, s2=0.f;
  for (int i=tid;i<720;i+=512){ float v=zr[i]; s+=v; s2+=v*v; }
  #pragma unroll
  for (int off=32; off>0; off>>=1){ s += __shfl_xor(s,off,64); s2 += __shfl_xor(s2,off,64); }
  if (lane==0){ redA[wave]=s; redB[wave]=s2; }
  __syncthreads();
  if (tid==0){
    float S=0.f,S2=0.f;
    #pragma unroll
    for (int w=0;w<8;++w){S+=redA[w];S2+=redB[w];}
    float mu = S*(1.f/720.f);
    float var = S2*(1.f/720.f) - mu*mu;
    stats[0]=mu; stats[1]=sqrtf(var+1e-5f);
  }
  __syncthreads();
  const float mu = stats[0], sd = stats[1], rsd = 1.f/sd;

  // ---- zn -> bufA (720 bf16, flat) ----
  for (int i=tid;i<720;i+=512) bufA[i] = f2bf((zr[i]-mu)*rsd);
  __syncthreads();

  // ---- patch embeds: x = zn-patches@WPw^T + WPb + PE ; pred = dummies[c]@WPw^T + WPb ----
  {
    const int m = lane&15, qd = lane>>4, col = wave*16+m;
    const short8 z8 = {0,0,0,0,0,0,0,0};
    short8 b = (qd<3) ? cvt8(WPw + col*24 + qd*8) : z8;        // K=24 pad 32, shared by rt
    const float bv = WPb[col];
    #pragma unroll
    for (int rt=0;rt<2;++rt){
      const int pm = rt*16+m;
      short8 ax = (pm<30 && qd<3) ? *(const short8*)(bufA + pm*24 + qd*8) : z8;
      short8 ap = (pm<30 && qd<3) ? cvt8(dums + c*720 + pm*24 + qd*8) : z8;
      floatx4 accx={0.f,0.f,0.f,0.f}, accp={0.f,0.f,0.f,0.f};
      accx = MFMA_BF16(ax,b,accx,0,0,0);
      accp = MFMA_BF16(ap,b,accp,0,0,0);
      #pragma unroll
      for (int r=0;r<4;++r){
        const int row = rt*16+qd*4+r;
        if (row<30){
          float pv = accp[r]+bv;
          x_s[row*SB+col]    = f2bf(accx[r]+bv+PE[row*128+col]);
          pred_s[row*SF+col] = pv;
          predb[row*SB+col]  = f2bf(pv);
        } else { x_s[row*SB+col]=0; predb[row*SB+col]=0; }
      }
    }
  }
  __syncthreads();

  // ---- cumulative attention scores in registers: lane owns (head h, query row p) ----
  float sc[30];
  #pragma unroll
  for (int i=0;i<30;++i) sc[i]=0.f;
  const int h = wave*2 + (lane>>5);
  const int p = lane & 31;

  for (int li=0; li<3; ++li){
    const WT* Wq = Wq_a + li*16384; const float* bq = bq_a + li*128;
    const WT* Wk = Wk_a + li*16384; const float* bk = bk_a + li*128;
    const WT* Wv = Wv_a + li*16384; const float* bv = bv_a + li*128;
    const WT* Wo = Wo_a + li*16384; const float* bo = bo_a + li*128;
    const WT* W1 = W1_a + li*32768; const float* b1 = b1_a + li*256;
    const WT* W2 = W2_a + li*16384; const float* b2 = b2_a + li*128;

    gemm_qk(predb, x_s, Wq, bq, Wk, bk, bufA, bufB, wave, lane);  // q->A, k->B
    __syncthreads();

    // score update + rowmax (q,k consumed here)
    float mx = 0.f;
    if (p < 30){
      short8 qq = *(const short8*)(bufA + p*SB + h*8);
      float qv[8];
      #pragma unroll
      for (int j=0;j<8;++j) qv[j]=bf2f((u16)qq[j]);
      #pragma unroll
      for (int si=0; si<30; ++si){
        short8 kk = *(const short8*)(bufB + si*SB + h*8);
        float d = 0.f;
        #pragma unroll
        for (int j=0;j<8;++j) d += qv[j]*bf2f((u16)kk[j]);
        sc[si] += d * ATTN_SCALE;                 // cumulative pre-softmax scores
      }
      mx = sc[0];
      #pragma unroll
      for (int si=1; si<30; ++si) mx = fmaxf(mx, sc[si]);
    }
    __syncthreads();

    gemm2(x_s, Wv, bv, bufA, wave, lane);         // v over q's buffer
    __syncthreads();

    // softmax + PV fused; o over k's buffer
    if (p < 30){
      float ssum = 0.f;
      float ov[8] = {0.f,0.f,0.f,0.f,0.f,0.f,0.f,0.f};
      #pragma unroll
      for (int si=0; si<30; ++si){
        float e = __expf(sc[si]-mx);
        ssum += e;
        short8 vv = *(const short8*)(bufA + si*SB + h*8);
        #pragma unroll
        for (int j=0;j<8;++j) ov[j] += e*bf2f((u16)vv[j]);
      }
      const float rn = 1.f/ssum;
      #pragma unroll
      for (int j=0;j<8;++j) bufB[p*SB+h*8+j] = f2bf(ov[j]*rn);
    }
    __syncthreads();

    gemm2(bufB, Wo, bo, bufA, wave, lane);                    // wo = o@Wo^T+bo
    __syncthreads();
    ln_res(pred_s, predb, bufA, g1_a+li*128, be1_a+li*128, wave, lane);
    __syncthreads();

    gemm_h(predb, W1, b1, bufB, wave, lane);                  // ag = a*gelu(gate)
    __syncthreads();
    gemm2(bufB, W2, b2, bufA, wave, lane);                    // f = ag@W2^T+b2
    __syncthreads();
    ln_res(pred_s, predb, bufA, g2_a+li*128, be2_a+li*128, wave, lane);
    __syncthreads();
  }

  // ---- head: out = (pred@proj_w^T + proj_b)*sd + mu ----
  {
    const int m = lane&15, qd = lane>>4;
    const short8 z8 = {0,0,0,0,0,0,0,0};
    float* orow = dout + bi*720;
    for (int t=wave; t<4; t+=8){
      const int rt=t>>1, ct=t&1;
      const int col = ct*16+m;                       // patch-len index 0..23 (pad 32)
      floatx4 acc = {0.f,0.f,0.f,0.f};
      #pragma unroll
      for (int kt=0;kt<4;++kt){
        const int k0 = kt*32+qd*8;
        short8 a = *(const short8*)(predb + (rt*16+m)*SB + k0);
        short8 b = (col<24) ? cvt8(PJw + col*128 + k0) : z8;
        acc = MFMA_BF16(a,b,acc,0,0,0);
      }
      if (col<24){
        const float pb = PJb[col];
        #pragma unroll
        for (int r=0;r<4;++r){
          const int row = rt*16+qd*4+r;
          if (row<30) orow[row*24+col] = (acc[r]+pb)*sd + mu;
        }
      }
    }
  }
}

extern "C" void kernel_launch(void* const* d_in, const int* in_sizes, int n_in,
                              void* d_out, int out_size, void* d_ws, size_t ws_size,
                              hipStream_t stream) {
  (void)in_sizes; (void)n_in; (void)out_size;
  const float* z    = (const float*)d_in[0];
  const float* WPw  = (const float*)d_in[1];
  const float* WPb  = (const float*)d_in[2];
  const float* PE   = (const float*)d_in[3];
  const float* dums = (const float*)d_in[4];
  const float* Wq   = (const float*)d_in[5];
  const float* bq   = (const float*)d_in[6];
  const float* Wk   = (const float*)d_in[7];
  const float* bk   = (const float*)d_in[8];
  const float* Wv   = (const float*)d_in[9];
  const float* bv   = (const float*)d_in[10];
  const float* Wo   = (const float*)d_in[11];
  const float* bo   = (const float*)d_in[12];
  const float* g1   = (const float*)d_in[13];
  const float* be1  = (const float*)d_in[14];
  const float* W1   = (const float*)d_in[15];
  const float* b1   = (const float*)d_in[16];
  const float* W2   = (const float*)d_in[17];
  const float* b2   = (const float*)d_in[18];
  const float* g2   = (const float*)d_in[19];
  const float* be2  = (const float*)d_in[20];
  const float* PJw  = (const float*)d_in[21];
  const float* PJb  = (const float*)d_in[22];
  float* dout = (float*)d_out;

  const size_t need = (size_t)344064 * sizeof(u16);   // 21*16384 bf16 weights
  if (ws_size >= need){
    u16* ws = (u16*)d_ws;
    cvtw<<<dim3(1344), dim3(256), 0, stream>>>(Wq, Wk, Wv, Wo, W1, W2, ws);
    ts_fused<u16><<<dim3(5136), dim3(512), 0, stream>>>(
      z, WPw, WPb, PE, dums,
      ws,        bq, ws+49152,  bk, ws+98304, bv, ws+147456, bo,
      g1, be1, ws+196608, b1, ws+294912, b2, g2, be2, PJw, PJb, dout);
  } else {
    ts_fused<float><<<dim3(5136), dim3(512), 0, stream>>>(
      z, WPw, WPb, PE, dums,
      Wq, bq, Wk, bk, Wv, bv, Wo, bo,
      g1, be1, W1, b1, W2, b2, g2, be2, PJw, PJb, dout);
  }
}

// Round 6
// 1009.493 us; speedup vs baseline: 1.2057x; 1.2057x over previous
//
#include <hip/hip_runtime.h>
#include <math.h>

// PatchTST-style fused forward, f32 in/out, bf16 MFMA compute.
// Round-6: spill elimination. Rounds 2-5 all had scratch spills (VGPR capped at
// 64/40 by occupancy-driven RA; WRITE_SIZE 0.8-1.7GB vs 15MB of real output).
// amdgpu_waves_per_eu(4,4) pins the RA target at 4 waves/EU -> full 128-VGPR
// budget -> sc[30] + batched fragments stay in registers. Structure = round 4
// (3 bufs, merged kv/h gemms, 7 barriers/layer); pred_s shrunk to 30 rows.
// LDS 59.4KB -> 2 blocks/CU (LDS-bound, same as round 4).

typedef unsigned short u16;
typedef __attribute__((ext_vector_type(8))) short short8;
typedef __attribute__((ext_vector_type(4))) float floatx4;

#define ATTN_SCALE 0.35355339059327373f  // 8^-0.5
#define SB 136   // bf16 LDS row stride: 272B = 68 dwords, 68%32=4 -> bank rotation
#define SF 132   // f32  LDS row stride: 132 dwords, 132%32=4

#define MFMA_BF16 __builtin_amdgcn_mfma_f32_16x16x32_bf16

__device__ __forceinline__ u16 f2bf(float f){
  union{float f; unsigned u;} v; v.f=f;
  unsigned r = v.u + 0x7FFFu + ((v.u>>16)&1u);   // RNE
  return (u16)(r>>16);
}
__device__ __forceinline__ float bf2f(u16 h){
  union{unsigned u; float f;} v; v.u = ((unsigned)h)<<16;
  return v.f;
}
__device__ __forceinline__ float gelu_f(float x){   // tanh-form gelu (sigmoid identity)
  float u = x*(1.f + 0.044715f*x*x);
  float e = __expf(-1.5957691216057308f*u);
  return x/(1.f+e);
}

// 8 f32 -> bf16 fragment (16B-aligned source)
__device__ __forceinline__ short8 cvt8(const float* ap){
  floatx4 f0 = *(const floatx4*)ap;
  floatx4 f1 = *(const floatx4*)(ap+4);
  short8 a;
  a[0]=(short)f2bf(f0[0]); a[1]=(short)f2bf(f0[1]);
  a[2]=(short)f2bf(f0[2]); a[3]=(short)f2bf(f0[3]);
  a[4]=(short)f2bf(f1[0]); a[5]=(short)f2bf(f1[1]);
  a[6]=(short)f2bf(f1[2]); a[7]=(short)f2bf(f1[3]);
  return a;
}
__device__ __forceinline__ short8 loadB(const u16* p){ return *(const short8*)p; }
__device__ __forceinline__ short8 loadB(const float* p){ return cvt8(p); }

// epilogue: store 4 acc rows (+bias) as bf16, zero rows >=30
__device__ __forceinline__ void epi(u16* out, floatx4 acc, float bv, int rt, int qd, int col){
  #pragma unroll
  for (int r=0;r<4;++r){
    const int row = rt*16+qd*4+r;
    out[row*SB+col] = (row<30) ? f2bf(acc[r]+bv) : (u16)0;
  }
}

// out(30x128) = A(32x128 LDS bf16) @ W^T + bias. Both row-tiles share B (ct=wave).
template<typename WT>
__device__ __forceinline__ void gemm2(const u16* A, const WT* __restrict__ W,
                                      const float* __restrict__ bias, u16* out,
                                      int wave, int lane){
  const int m=lane&15, qd=lane>>4, col=wave*16+m;
  short8 b4[4];
  #pragma unroll
  for (int kt=0;kt<4;++kt) b4[kt] = loadB(W + col*128 + kt*32 + qd*8);
  const float bv = bias[col];
  #pragma unroll
  for (int rt=0;rt<2;++rt){
    short8 a4[4];
    #pragma unroll
    for (int kt=0;kt<4;++kt) a4[kt] = *(const short8*)(A + (rt*16+m)*SB + kt*32 + qd*8);
    floatx4 acc = {0.f,0.f,0.f,0.f};
    #pragma unroll
    for (int kt=0;kt<4;++kt) acc = MFMA_BF16(a4[kt], b4[kt], acc, 0,0,0);
    epi(out, acc, bv, rt, qd, col);
  }
}

// k and v gemms from shared A = x_s: 8 B-loads batched, A-reads shared.
template<typename WT>
__device__ __forceinline__ void gemm_kv(const u16* A,
                                        const WT* __restrict__ Wk, const float* __restrict__ bk,
                                        const WT* __restrict__ Wv, const float* __restrict__ bv_,
                                        u16* outk, u16* outv, int wave, int lane){
  const int m=lane&15, qd=lane>>4, col=wave*16+m;
  short8 bkf[4], bvf[4];
  #pragma unroll
  for (int kt=0;kt<4;++kt) bkf[kt] = loadB(Wk + col*128 + kt*32 + qd*8);
  #pragma unroll
  for (int kt=0;kt<4;++kt) bvf[kt] = loadB(Wv + col*128 + kt*32 + qd*8);
  const float bkb = bk[col], bvb = bv_[col];
  #pragma unroll
  for (int rt=0;rt<2;++rt){
    short8 a4[4];
    #pragma unroll
    for (int kt=0;kt<4;++kt) a4[kt] = *(const short8*)(A + (rt*16+m)*SB + kt*32 + qd*8);
    floatx4 acck = {0.f,0.f,0.f,0.f}, accv = {0.f,0.f,0.f,0.f};
    #pragma unroll
    for (int kt=0;kt<4;++kt){
      acck = MFMA_BF16(a4[kt], bkf[kt], acck, 0,0,0);
      accv = MFMA_BF16(a4[kt], bvf[kt], accv, 0,0,0);
    }
    epi(outk, acck, bkb, rt, qd, col);
    epi(outv, accv, bvb, rt, qd, col);
  }
}

// FF up: h = pred@W1^T (256 cols); writes ag = a * gelu(gate) directly.
template<typename WT>
__device__ __forceinline__ void gemm_h(const u16* A, const WT* __restrict__ W1,
                                       const float* __restrict__ b1, u16* out,
                                       int wave, int lane){
  const int m=lane&15, qd=lane>>4, col=wave*16+m;
  short8 ba4[4], bg4[4];
  #pragma unroll
  for (int kt=0;kt<4;++kt) ba4[kt] = loadB(W1 + col*128 + kt*32 + qd*8);
  #pragma unroll
  for (int kt=0;kt<4;++kt) bg4[kt] = loadB(W1 + (128+col)*128 + kt*32 + qd*8);
  const float bab = b1[col], bgb = b1[128+col];
  #pragma unroll
  for (int rt=0;rt<2;++rt){
    short8 a4[4];
    #pragma unroll
    for (int kt=0;kt<4;++kt) a4[kt] = *(const short8*)(A + (rt*16+m)*SB + kt*32 + qd*8);
    floatx4 acca = {0.f,0.f,0.f,0.f}, accg = {0.f,0.f,0.f,0.f};
    #pragma unroll
    for (int kt=0;kt<4;++kt){
      acca = MFMA_BF16(a4[kt], ba4[kt], acca, 0,0,0);
      accg = MFMA_BF16(a4[kt], bg4[kt], accg, 0,0,0);
    }
    #pragma unroll
    for (int r=0;r<4;++r){
      const int row = rt*16+qd*4+r;
      u16 res = 0;
      if (row<30){
        float a = acca[r]+bab;
        float g = accg[r]+bgb;
        res = f2bf(a * gelu_f(g));
      }
      out[row*SB+col] = res;
    }
  }
}

// pred = LN(pred + bf16(add)) * g + be, rows 0..29; maintains bf16 mirror predb
__device__ __forceinline__ void ln_res(float* pred, u16* predb, const u16* add,
                                       const float* __restrict__ g, const float* __restrict__ be,
                                       int wave, int lane){
  for (int rr=wave; rr<30; rr+=8){
    float* pr = pred + rr*SF;
    u16*  pbr = predb + rr*SB;
    const u16* ar = add + rr*SB;
    float v0 = pr[lane]    + bf2f(ar[lane]);
    float v1 = pr[lane+64] + bf2f(ar[lane+64]);
    float s = v0+v1, s2 = v0*v0+v1*v1;
    #pragma unroll
    for (int off=32; off>0; off>>=1){ s += __shfl_xor(s,off,64); s2 += __shfl_xor(s2,off,64); }
    float m = s*(1.f/128.f);
    float var = s2*(1.f/128.f) - m*m;
    float rstd = rsqrtf(var + 1e-5f);
    float o0 = (v0-m)*rstd*g[lane]    + be[lane];
    float o1 = (v1-m)*rstd*g[lane+64] + be[lane+64];
    pr[lane] = o0; pr[lane+64] = o1;
    pbr[lane] = f2bf(o0); pbr[lane+64] = f2bf(o1);
  }
}

// f32 -> bf16 weight staging
__global__ void cvtw(const float* __restrict__ Wq, const float* __restrict__ Wk,
                     const float* __restrict__ Wv, const float* __restrict__ Wo,
                     const float* __restrict__ W1, const float* __restrict__ W2,
                     u16* __restrict__ ws){
  const int i = blockIdx.x*256 + threadIdx.x;   // grid covers exactly 344064
  float v;
  if      (i < 49152)  v = Wq[i];
  else if (i < 98304)  v = Wk[i-49152];
  else if (i < 147456) v = Wv[i-98304];
  else if (i < 196608) v = Wo[i-147456];
  else if (i < 294912) v = W1[i-196608];
  else                 v = W2[i-294912];
  ws[i] = f2bf(v);
}

template<typename WT>
__global__ void
__attribute__((amdgpu_flat_work_group_size(512,512), amdgpu_waves_per_eu(4,4)))
ts_fused(
  const float* __restrict__ z,    const float* __restrict__ WPw, const float* __restrict__ WPb,
  const float* __restrict__ PE,   const float* __restrict__ dums,
  const WT*    __restrict__ Wq_a, const float* __restrict__ bq_a,
  const WT*    __restrict__ Wk_a, const float* __restrict__ bk_a,
  const WT*    __restrict__ Wv_a, const float* __restrict__ bv_a,
  const WT*    __restrict__ Wo_a, const float* __restrict__ bo_a,
  const float* __restrict__ g1_a, const float* __restrict__ be1_a,
  const WT*    __restrict__ W1_a, const float* __restrict__ b1_a,
  const WT*    __restrict__ W2_a, const float* __restrict__ b2_a,
  const float* __restrict__ g2_a, const float* __restrict__ be2_a,
  const float* __restrict__ PJw,  const float* __restrict__ PJb,
  float* __restrict__ dout)
{
  __shared__ __align__(16) u16   x_s[32*SB];      // encoder tokens (rows 30,31 = 0)
  __shared__ __align__(16) u16   predb[32*SB];    // bf16 mirror of pred
  __shared__ __align__(16) float pred_s[30*SF];   // decoder state, f32 (30 rows)
  __shared__ __align__(16) u16   bufA[32*SB];     // zn / q+o
  __shared__ __align__(16) u16   bufB[32*SB];     // k / wo / f
  __shared__ __align__(16) u16   bufC[32*SB];     // v / ag
  __shared__ float redA[8], redB[8], stats[2];

  const int tid  = threadIdx.x;
  const int wave = tid >> 6;
  const int lane = tid & 63;
  const int bi   = blockIdx.x;          // 0..5135 = b*321+c
  const int c    = bi % 321;
  const float* zr = z + bi*720;

  // ---- per-series mean/std over 720 samples ----
  float s=0.f, s2=0.f;
  for (int i=tid;i<720;i+=512){ float v=zr[i]; s+=v; s2+=v*v; }
  #pragma unroll
  for (int off=32; off>0; off>>=1){ s += __shfl_xor(s,off,64); s2 += __shfl_xor(s2,off,64); }
  if (lane==0){ redA[wave]=s; redB[wave]=s2; }
  __syncthreads();
  if (tid==0){
    float S=0.f,S2=0.f;
    #pragma unroll
    for (int w=0;w<8;++w){S+=redA[w];S2+=redB[w];}
    float mu = S*(1.f/720.f);
    float var = S2*(1.f/720.f) - mu*mu;
    stats[0]=mu; stats[1]=sqrtf(var+1e-5f);
  }
  __syncthreads();
  const float mu = stats[0], sd = stats[1], rsd = 1.f/sd;

  // ---- zn -> bufA (720 bf16, flat) ----
  for (int i=tid;i<720;i+=512) bufA[i] = f2bf((zr[i]-mu)*rsd);
  __syncthreads();

  // ---- patch embeds: x = zn-patches@WPw^T + WPb + PE ; pred = dummies[c]@WPw^T + WPb ----
  {
    const int m = lane&15, qd = lane>>4, col = wave*16+m;
    const short8 z8 = {0,0,0,0,0,0,0,0};
    short8 b = (qd<3) ? cvt8(WPw + col*24 + qd*8) : z8;        // K=24 pad 32, shared by rt
    const float bv = WPb[col];
    #pragma unroll
    for (int rt=0;rt<2;++rt){
      const int pm = rt*16+m;
      short8 ax = (pm<30 && qd<3) ? *(const short8*)(bufA + pm*24 + qd*8) : z8;
      short8 ap = (pm<30 && qd<3) ? cvt8(dums + c*720 + pm*24 + qd*8) : z8;
      floatx4 accx={0.f,0.f,0.f,0.f}, accp={0.f,0.f,0.f,0.f};
      accx = MFMA_BF16(ax,b,accx,0,0,0);
      accp = MFMA_BF16(ap,b,accp,0,0,0);
      #pragma unroll
      for (int r=0;r<4;++r){
        const int row = rt*16+qd*4+r;
        if (row<30){
          float pv = accp[r]+bv;
          x_s[row*SB+col]    = f2bf(accx[r]+bv+PE[row*128+col]);
          pred_s[row*SF+col] = pv;
          predb[row*SB+col]  = f2bf(pv);
        } else { x_s[row*SB+col]=0; predb[row*SB+col]=0; }
      }
    }
  }
  __syncthreads();

  // ---- cumulative attention scores in registers: lane owns (head h, query row p) ----
  float sc[30];
  #pragma unroll
  for (int i=0;i<30;++i) sc[i]=0.f;
  const int h = wave*2 + (lane>>5);
  const int p = lane & 31;

  for (int li=0; li<3; ++li){
    const WT* Wq = Wq_a + li*16384; const float* bq = bq_a + li*128;
    const WT* Wk = Wk_a + li*16384; const float* bk = bk_a + li*128;
    const WT* Wv = Wv_a + li*16384; const float* bv = bv_a + li*128;
    const WT* Wo = Wo_a + li*16384; const float* bo = bo_a + li*128;
    const WT* W1 = W1_a + li*32768; const float* b1 = b1_a + li*256;
    const WT* W2 = W2_a + li*16384; const float* b2 = b2_a + li*128;

    gemm2  (predb, Wq, bq, bufA, wave, lane);                 // q
    gemm_kv(x_s, Wk, bk, Wv, bv, bufB, bufC, wave, lane);     // k, v (shared A)
    __syncthreads();

    if (p < 30){
      short8 qq = *(const short8*)(bufA + p*SB + h*8);
      float qv[8];
      #pragma unroll
      for (int j=0;j<8;++j) qv[j]=bf2f((u16)qq[j]);
      #pragma unroll
      for (int si=0; si<30; ++si){
        short8 kk = *(const short8*)(bufB + si*SB + h*8);
        float d = 0.f;
        #pragma unroll
        for (int j=0;j<8;++j) d += qv[j]*bf2f((u16)kk[j]);
        sc[si] += d * ATTN_SCALE;                 // cumulative pre-softmax scores
      }
      float mx = sc[0];
      #pragma unroll
      for (int si=1; si<30; ++si) mx = fmaxf(mx, sc[si]);
      float ssum = 0.f;
      float ov[8] = {0.f,0.f,0.f,0.f,0.f,0.f,0.f,0.f};
      #pragma unroll
      for (int si=0; si<30; ++si){
        float e = __expf(sc[si]-mx);
        ssum += e;
        short8 vv = *(const short8*)(bufC + si*SB + h*8);
        #pragma unroll
        for (int j=0;j<8;++j) ov[j] += e*bf2f((u16)vv[j]);
      }
      const float rn = 1.f/ssum;
      #pragma unroll
      for (int j=0;j<8;++j) bufA[p*SB+h*8+j] = f2bf(ov[j]*rn);  // o over own q slot
    }
    __syncthreads();

    gemm2(bufA, Wo, bo, bufB, wave, lane);                    // wo = o@Wo^T+bo
    __syncthreads();
    ln_res(pred_s, predb, bufB, g1_a+li*128, be1_a+li*128, wave, lane);
    __syncthreads();

    gemm_h(predb, W1, b1, bufC, wave, lane);                  // ag = a*gelu(gate)
    __syncthreads();
    gemm2(bufC, W2, b2, bufB, wave, lane);                    // f = ag@W2^T+b2
    __syncthreads();
    ln_res(pred_s, predb, bufB, g2_a+li*128, be2_a+li*128, wave, lane);
    __syncthreads();
  }

  // ---- head: out = (pred@proj_w^T + proj_b)*sd + mu ----
  {
    const int m = lane&15, qd = lane>>4;
    const short8 z8 = {0,0,0,0,0,0,0,0};
    float* orow = dout + bi*720;
    for (int t=wave; t<4; t+=8){
      const int rt=t>>1, ct=t&1;
      const int col = ct*16+m;                       // patch-len index 0..23 (pad 32)
      floatx4 acc = {0.f,0.f,0.f,0.f};
      #pragma unroll
      for (int kt=0;kt<4;++kt){
        const int k0 = kt*32+qd*8;
        short8 a = *(const short8*)(predb + (rt*16+m)*SB + k0);
        short8 b = (col<24) ? cvt8(PJw + col*128 + k0) : z8;
        acc = MFMA_BF16(a,b,acc,0,0,0);
      }
      if (col<24){
        const float pb = PJb[col];
        #pragma unroll
        for (int r=0;r<4;++r){
          const int row = rt*16+qd*4+r;
          if (row<30) orow[row*24+col] = (acc[r]+pb)*sd + mu;
        }
      }
    }
  }
}

extern "C" void kernel_launch(void* const* d_in, const int* in_sizes, int n_in,
                              void* d_out, int out_size, void* d_ws, size_t ws_size,
                              hipStream_t stream) {
  (void)in_sizes; (void)n_in; (void)out_size;
  const float* z    = (const float*)d_in[0];
  const float* WPw  = (const float*)d_in[1];
  const float* WPb  = (const float*)d_in[2];
  const float* PE   = (const float*)d_in[3];
  const float* dums = (const float*)d_in[4];
  const float* Wq   = (const float*)d_in[5];
  const float* bq   = (const float*)d_in[6];
  const float* Wk   = (const float*)d_in[7];
  const float* bk   = (const float*)d_in[8];
  const float* Wv   = (const float*)d_in[9];
  const float* bv   = (const float*)d_in[10];
  const float* Wo   = (const float*)d_in[11];
  const float* bo   = (const float*)d_in[12];
  const float* g1   = (const float*)d_in[13];
  const float* be1  = (const float*)d_in[14];
  const float* W1   = (const float*)d_in[15];
  const float* b1   = (const float*)d_in[16];
  const float* W2   = (const float*)d_in[17];
  const float* b2   = (const float*)d_in[18];
  const float* g2   = (const float*)d_in[19];
  const float* be2  = (const float*)d_in[20];
  const float* PJw  = (const float*)d_in[21];
  const float* PJb  = (const float*)d_in[22];
  float* dout = (float*)d_out;

  const size_t need = (size_t)344064 * sizeof(u16);   // 21*16384 bf16 weights
  if (ws_size >= need){
    u16* ws = (u16*)d_ws;
    cvtw<<<dim3(1344), dim3(256), 0, stream>>>(Wq, Wk, Wv, Wo, W1, W2, ws);
    ts_fused<u16><<<dim3(5136), dim3(512), 0, stream>>>(
      z, WPw, WPb, PE, dums,
      ws,        bq, ws+49152,  bk, ws+98304, bv, ws+147456, bo,
      g1, be1, ws+196608, b1, ws+294912, b2, g2, be2, PJw, PJb, dout);
  } else {
    ts_fused<float><<<dim3(5136), dim3(512), 0, stream>>>(
      z, WPw, WPb, PE, dums,
      Wq, bq, Wk, bk, Wv, bv, Wo, bo,
      g1, be1, W1, b1, W2, b2, g2, be2, PJw, PJb, dout);
  }
}